// Round 2
// baseline (234.132 us; speedup 1.0000x reference)
//
#include <hip/hip_runtime.h>
#include <math.h>

#define BB 32
#define TT 8192
#define AD 128
#define NF 32
#define KW 31

// ws layout (floats) — only 32 KB used:
#define WS_MT  0       // Mt[31][128]  (M transposed: Mt[k][a] = sum_f L_w[a][f]*conv_w[f][k])
#define WS_PQC 4096    // pqc[B][128]  (query@W_w.T + W_b + L_w@conv_b)
// u[B][T] lives in d_out; softmax runs in-place.

__device__ __forceinline__ float fast_tanh(float x) {
  x = fminf(8.f, fmaxf(-8.f, x));
  float e = __expf(2.f * x);
  return (e - 1.f) * __builtin_amdgcn_rcpf(e + 1.f);
}

// ---------------- kernel 0: tiny precompute ----------------
__global__ void __launch_bounds__(128) precompute_kernel(
    const float* __restrict__ query, const float* __restrict__ conv_w,
    const float* __restrict__ conv_b, const float* __restrict__ L_w,
    const float* __restrict__ W_w, const float* __restrict__ W_b,
    float* __restrict__ ws) {
  const int a = threadIdx.x;   // 0..127
  const int blk = blockIdx.x;  // 0..32
  if (blk < BB) {
    // pqc[blk][a] = sum_d query[blk][d]*W_w[a][d] + W_b[a] + sum_f L_w[a][f]*conv_b[f]
    float acc = W_b[a];
    const float* q = query + blk * AD;
    const float* w = W_w + a * AD;
#pragma unroll 8
    for (int d = 0; d < AD; ++d) acc = fmaf(q[d], w[d], acc);
    float c0 = 0.f;
#pragma unroll
    for (int f = 0; f < NF; ++f) c0 = fmaf(L_w[a * NF + f], conv_b[f], c0);
    ws[WS_PQC + blk * AD + a] = acc + c0;
  } else {
    // Mt[k][a] = sum_f L_w[a][f] * conv_w[f][k]
#pragma unroll 1
    for (int k = 0; k < KW; ++k) {
      float m = 0.f;
#pragma unroll
      for (int f = 0; f < NF; ++f) m = fmaf(L_w[a * NF + f], conv_w[f * KW + k], m);
      ws[WS_MT + k * AD + a] = m;
    }
  }
}

// ---------------- kernel 1: fused conv+proj+tanh+dot -> u ----------------
// grid (T/256, B), block 256. Wave wv owns t in [t0+64*wv, t0+64*wv+64).
// Lane owns channels (2*lane, 2*lane+1). M rows live in registers (62 VGPR).
__global__ void __launch_bounds__(256, 3) lsa_u_kernel(
    const float* __restrict__ enc, const float* __restrict__ cum,
    const int* __restrict__ chars, const float* __restrict__ v_w,
    const float* __restrict__ ws, float* __restrict__ uout_all) {
  __shared__ __attribute__((aligned(16))) float lcum[304];
  const int b = blockIdx.y;
  const int t0 = blockIdx.x * 256;

  // stage cum[t0-16 .. t0+287] with zero padding at sequence edges
  for (int i = threadIdx.x; i < 304; i += 256) {
    int g = t0 - 16 + i;
    lcum[i] = (g >= 0 && g < TT) ? cum[b * TT + g] : 0.f;
  }
  __syncthreads();

  const int lane = threadIdx.x & 63;
  const int wv = threadIdx.x >> 6;
  const int a0 = lane * 2;

  float M0[KW], M1[KW];
#pragma unroll
  for (int k = 0; k < KW; ++k) {
    float2 m = *(const float2*)&ws[WS_MT + k * AD + a0];
    M0[k] = m.x; M1[k] = m.y;
  }
  const float2 pq = *(const float2*)&ws[WS_PQC + b * AD + a0];
  const float2 vv = *(const float2*)&v_w[a0];

  const int ts_w = t0 + wv * 64;
  const float* encb = enc + ((size_t)b * TT + ts_w) * AD + a0;
  const int* chb = chars + b * TT + ts_w;
  float* uout = uout_all + (size_t)b * TT + ts_w;

  // prefetch first 8-t group of enc
  float2 ecur[8];
#pragma unroll
  for (int j = 0; j < 8; ++j) ecur[j] = *(const float2*)(encb + (size_t)j * AD);

#pragma unroll 1
  for (int g = 0; g < 8; ++g) {
    const int tloc = g * 8;
    // prefetch next group's enc while this group computes
    float2 enx[8];
    if (g < 7) {
#pragma unroll
      for (int j = 0; j < 8; ++j)
        enx[j] = *(const float2*)(encb + (size_t)(tloc + 8 + j) * AD);
    }
    // wave-uniform cum window: w[i] = cum[ts-16+i], i in [0,40)
    float w[40];
    const float4* w4 = (const float4*)&lcum[wv * 64 + tloc];
#pragma unroll
    for (int i = 0; i < 10; ++i) {
      float4 f = w4[i];
      w[4 * i] = f.x; w[4 * i + 1] = f.y; w[4 * i + 2] = f.z; w[4 * i + 3] = f.w;
    }
    float ureg = 0.f;
#pragma unroll
    for (int j = 0; j < 8; ++j) {
      const int ch = chb[tloc + j];   // wave-uniform -> scalar load
      float p0 = 0.f, p1 = 0.f;
      // conv: cum[t+k-15] = w[j+k+1]
#pragma unroll
      for (int k = 0; k < KW; ++k) {
        const float c = w[j + k + 1];
        p0 = fmaf(M0[k], c, p0);
        p1 = fmaf(M1[k], c, p1);
      }
      const float x0 = pq.x + ecur[j].x + p0;
      const float x1 = pq.y + ecur[j].y + p1;
      float s = fast_tanh(x0) * vv.x + fast_tanh(x1) * vv.y;
      // 128-channel dot: butterfly over the 64 lanes (each lane holds 2 ch)
#pragma unroll
      for (int off = 32; off >= 1; off >>= 1) s += __shfl_xor(s, off);
      s = (ch != 0) ? s : 0.f;
      ureg = (lane == j) ? s : ureg;   // lane j keeps u(t=ts+j)
    }
    if (lane < 8) uout[tloc + lane] = ureg;  // 32B coalesced store
    if (g < 7) {
#pragma unroll
      for (int j = 0; j < 8; ++j) ecur[j] = enx[j];
    }
  }
}

// ---------------- kernel 2: row softmax over T (in-place on d_out) ----------------
__global__ void __launch_bounds__(1024) softmax_kernel(float* __restrict__ uio) {
  __shared__ float redm[16], reds[16];
  const int b = blockIdx.x;
  float* u = uio + (size_t)b * TT;
  const int tid = threadIdx.x;
  const int lane = tid & 63, wv = tid >> 6;
  float v[8];
#pragma unroll
  for (int i = 0; i < 8; ++i) v[i] = u[i * 1024 + tid];
  float mx = v[0];
#pragma unroll
  for (int i = 1; i < 8; ++i) mx = fmaxf(mx, v[i]);
#pragma unroll
  for (int off = 32; off >= 1; off >>= 1) mx = fmaxf(mx, __shfl_xor(mx, off));
  if (lane == 0) redm[wv] = mx;
  __syncthreads();
  mx = redm[0];
#pragma unroll
  for (int i = 1; i < 16; ++i) mx = fmaxf(mx, redm[i]);

  float e[8];
  float sum = 0.f;
#pragma unroll
  for (int i = 0; i < 8; ++i) { e[i] = __expf(v[i] - mx); sum += e[i]; }
#pragma unroll
  for (int off = 32; off >= 1; off >>= 1) sum += __shfl_xor(sum, off);
  if (lane == 0) reds[wv] = sum;
  __syncthreads();
  sum = 0.f;
#pragma unroll
  for (int i = 0; i < 16; ++i) sum += reds[i];
  const float inv = __builtin_amdgcn_rcpf(sum);
#pragma unroll
  for (int i = 0; i < 8; ++i) u[i * 1024 + tid] = e[i] * inv;
}

extern "C" void kernel_launch(void* const* d_in, const int* in_sizes, int n_in,
                              void* d_out, int out_size, void* d_ws, size_t ws_size,
                              hipStream_t stream) {
  const float* enc    = (const float*)d_in[0];
  const float* query  = (const float*)d_in[1];
  const float* cum    = (const float*)d_in[2];
  const int*   chars  = (const int*)d_in[3];
  // d_in[4] = t (unused by the computation)
  const float* conv_w = (const float*)d_in[5];
  const float* conv_b = (const float*)d_in[6];
  const float* L_w    = (const float*)d_in[7];
  const float* W_w    = (const float*)d_in[8];
  const float* W_b    = (const float*)d_in[9];
  const float* v_w    = (const float*)d_in[10];
  float* ws  = (float*)d_ws;
  float* out = (float*)d_out;

  hipLaunchKernelGGL(precompute_kernel, dim3(BB + 1), dim3(AD), 0, stream,
                     query, conv_w, conv_b, L_w, W_w, W_b, ws);
  hipLaunchKernelGGL(lsa_u_kernel, dim3(TT / 256, BB), dim3(256), 0, stream,
                     enc, cum, chars, v_w, ws, out);
  hipLaunchKernelGGL(softmax_kernel, dim3(BB), dim3(1024), 0, stream, out);
}

// Round 3
// 228.349 us; speedup vs baseline: 1.0253x; 1.0253x over previous
//
#include <hip/hip_runtime.h>
#include <math.h>

#define BB 32
#define TT 8192
#define AD 128
#define NF 32
#define KW 31

// ws layout (floats):
#define WS_MT   0      // MtC2[31][128], pre-scaled by 2*log2(e)
#define WS_PQC  4096   // pqcC2[B][128], pre-scaled by 2*log2(e)
#define WS_PMAX 8192   // [B][8] chunk maxes
#define WS_PSUM 8448   // [B][8] chunk sums

typedef float f32x2 __attribute__((ext_vector_type(2)));
#define C2F 2.885390081777927f   // 2*log2(e)

// packed dual-FMA with the S1 operand broadcast from its LO / HI half
__device__ __forceinline__ f32x2 pk_fma_b_lo(f32x2 m, f32x2 w, f32x2 p) {
  asm("v_pk_fma_f32 %0, %1, %2, %0 op_sel_hi:[1,0,1]" : "+v"(p) : "v"(m), "v"(w));
  return p;
}
__device__ __forceinline__ f32x2 pk_fma_b_hi(f32x2 m, f32x2 w, f32x2 p) {
  asm("v_pk_fma_f32 %0, %1, %2, %0 op_sel:[0,1,0]" : "+v"(p) : "v"(m), "v"(w));
  return p;
}

// ---------------- kernel 0: tiny precompute ----------------
__global__ void __launch_bounds__(128) precompute_kernel(
    const float* __restrict__ query, const float* __restrict__ conv_w,
    const float* __restrict__ conv_b, const float* __restrict__ L_w,
    const float* __restrict__ W_w, const float* __restrict__ W_b,
    float* __restrict__ ws) {
  const int a = threadIdx.x;   // 0..127
  const int blk = blockIdx.x;  // 0..32
  if (blk < BB) {
    float acc = W_b[a];
    const float* q = query + blk * AD;
    const float* w = W_w + a * AD;
#pragma unroll 8
    for (int d = 0; d < AD; ++d) acc = fmaf(q[d], w[d], acc);
    float c0 = 0.f;
#pragma unroll
    for (int f = 0; f < NF; ++f) c0 = fmaf(L_w[a * NF + f], conv_b[f], c0);
    ws[WS_PQC + blk * AD + a] = (acc + c0) * C2F;
  } else {
#pragma unroll 1
    for (int k = 0; k < KW; ++k) {
      float m = 0.f;
#pragma unroll
      for (int f = 0; f < NF; ++f) m = fmaf(L_w[a * NF + f], conv_w[f * KW + k], m);
      ws[WS_MT + k * AD + a] = m * C2F;
    }
  }
}

// ---------------- kernel 1: fused conv+proj+tanh+dot -> u ----------------
// grid (T/128, B), block 256 (4 waves). Wave owns 32 t's; lane owns channel
// pair (2*lane, 2*lane+1); M pairs in registers; conv via v_pk_fma_f32.
__global__ void __launch_bounds__(256, 3) lsa_u_kernel(
    const float* __restrict__ enc, const float* __restrict__ cum,
    const int* __restrict__ chars, const float* __restrict__ v_w,
    const float* __restrict__ ws, float* __restrict__ uout_all) {
  __shared__ __attribute__((aligned(16))) float lcum[160];
  const int b = blockIdx.y;
  const int t0 = blockIdx.x * 128;

  for (int i = threadIdx.x; i < 160; i += 256) {
    int g = t0 - 16 + i;
    lcum[i] = (g >= 0 && g < TT) ? cum[b * TT + g] : 0.f;
  }
  __syncthreads();

  const int lane = threadIdx.x & 63;
  const int wv = threadIdx.x >> 6;
  const int a0 = lane * 2;

  f32x2 Mv[KW];
#pragma unroll
  for (int k = 0; k < KW; ++k)
    Mv[k] = *(const f32x2*)&ws[WS_MT + k * AD + a0];
  const f32x2 pqC = *(const f32x2*)&ws[WS_PQC + b * AD + a0];
  const float2 vvw = *(const float2*)&v_w[a0];
  const float w0n = -2.f * vvw.x, w1n = -2.f * vvw.y, vsum = vvw.x + vvw.y;
  const f32x2 c2v = {C2F, C2F};

  const int ts_w = t0 + wv * 32;
  const float* encb = enc + ((size_t)b * TT + ts_w) * AD + a0;
  const int* chb = chars + b * TT + ts_w;
  float* uout = uout_all + (size_t)b * TT + ts_w;

  f32x2 ecur[8];
#pragma unroll
  for (int j = 0; j < 8; ++j) ecur[j] = *(const f32x2*)(encb + (size_t)j * AD);

#pragma unroll 1
  for (int g = 0; g < 4; ++g) {
    const int tloc = g * 8;
    f32x2 enx[8];
    if (g < 3) {
#pragma unroll
      for (int j = 0; j < 8; ++j)
        enx[j] = *(const f32x2*)(encb + (size_t)(tloc + 8 + j) * AD);
    }
    // window pairs: wp[m] = (w[2m], w[2m+1]), w[i] = cum[ts+tloc-16+i]
    f32x2 wp[20];
    const f32x2* wsrc = (const f32x2*)&lcum[wv * 32 + tloc];
#pragma unroll
    for (int m = 0; m < 20; ++m) wp[m] = wsrc[m];

    float s[8];
#pragma unroll
    for (int j = 0; j < 8; ++j) {
      f32x2 p = {0.f, 0.f};
#pragma unroll
      for (int k = 0; k < KW; ++k) {
        const int i = j + k + 1;           // compile-time constant
        if ((i & 1) == 0) p = pk_fma_b_lo(Mv[k], wp[i >> 1], p);
        else              p = pk_fma_b_hi(Mv[k], wp[i >> 1], p);
      }
      const f32x2 xin = ecur[j] * c2v + pqC + p;   // scaled by 2*log2e
      const float z0 = exp2f(xin.x), z1 = exp2f(xin.y);
      const float r0 = __builtin_amdgcn_rcpf(z0 + 1.f);
      const float r1 = __builtin_amdgcn_rcpf(z1 + 1.f);
      // v0*tanh0 + v1*tanh1 = vsum - 2 v0 r0 - 2 v1 r1
      s[j] = fmaf(w0n, r0, fmaf(w1n, r1, vsum));
    }

    // multi-value butterfly: U[j] = sum over 64 lanes of s[j]
    const bool b0 = lane & 1;
    float a4[4];
#pragma unroll
    for (int i = 0; i < 4; ++i) {
      float snd = b0 ? s[i] : s[i + 4];
      float rcv = __shfl_xor(snd, 1);
      a4[i] = (b0 ? s[i + 4] : s[i]) + rcv;
    }
    const bool b1 = lane & 2;
    float a2[2];
#pragma unroll
    for (int i = 0; i < 2; ++i) {
      float snd = b1 ? a4[i] : a4[i + 2];
      float rcv = __shfl_xor(snd, 2);
      a2[i] = (b1 ? a4[i + 2] : a4[i]) + rcv;
    }
    const bool b2v = lane & 4;
    {
      float snd = b2v ? a2[0] : a2[1];
      float rcv = __shfl_xor(snd, 4);
      float acc = (b2v ? a2[1] : a2[0]) + rcv;
      acc += __shfl_xor(acc, 8);
      acc += __shfl_xor(acc, 16);
      acc += __shfl_xor(acc, 32);
      // lane l (l<8) holds U[bitrev3(l)]
      if (lane < 8) {
        const int j = ((lane & 1) << 2) | (lane & 2) | ((lane >> 2) & 1);
        const int ch = chb[tloc + j];
        uout[tloc + j] = (ch != 0) ? acc : 0.f;
      }
    }
    if (g < 3) {
#pragma unroll
      for (int j = 0; j < 8; ++j) ecur[j] = enx[j];
    }
  }
}

// ---------------- kernel 2a: per-chunk max & sumexp ----------------
__global__ void __launch_bounds__(256) smax_partial(
    const float* __restrict__ u, float* __restrict__ ws) {
  __shared__ float rm[4], rs[4];
  const int c = blockIdx.x, b = blockIdx.y;
  const float* ub = u + (size_t)b * TT + c * 1024;
  const int tid = threadIdx.x;
  const int lane = tid & 63, wv = tid >> 6;
  const float v0 = ub[tid], v1 = ub[tid + 256], v2 = ub[tid + 512], v3 = ub[tid + 768];
  float mx = fmaxf(fmaxf(v0, v1), fmaxf(v2, v3));
#pragma unroll
  for (int off = 32; off >= 1; off >>= 1) mx = fmaxf(mx, __shfl_xor(mx, off));
  if (lane == 0) rm[wv] = mx;
  __syncthreads();
  mx = fmaxf(fmaxf(rm[0], rm[1]), fmaxf(rm[2], rm[3]));
  float sum = __expf(v0 - mx) + __expf(v1 - mx) + __expf(v2 - mx) + __expf(v3 - mx);
#pragma unroll
  for (int off = 32; off >= 1; off >>= 1) sum += __shfl_xor(sum, off);
  if (lane == 0) rs[wv] = sum;
  __syncthreads();
  if (tid == 0) {
    ws[WS_PMAX + b * 8 + c] = mx;
    ws[WS_PSUM + b * 8 + c] = rs[0] + rs[1] + rs[2] + rs[3];
  }
}

// ---------------- kernel 2b: normalize (in-place on d_out) ----------------
__global__ void __launch_bounds__(256) smax_norm(
    float* __restrict__ uio, const float* __restrict__ ws) {
  const int c = blockIdx.x, b = blockIdx.y;
  float gm = -1e30f;
#pragma unroll
  for (int i = 0; i < 8; ++i) gm = fmaxf(gm, ws[WS_PMAX + b * 8 + i]);
  float gs = 0.f;
#pragma unroll
  for (int i = 0; i < 8; ++i)
    gs += ws[WS_PSUM + b * 8 + i] * __expf(ws[WS_PMAX + b * 8 + i] - gm);
  const float inv = 1.f / gs;
  float* ub = uio + (size_t)b * TT + c * 1024;
  const int tid = threadIdx.x;
#pragma unroll
  for (int i = 0; i < 4; ++i) {
    const int idx = tid + i * 256;
    ub[idx] = __expf(ub[idx] - gm) * inv;
  }
}

extern "C" void kernel_launch(void* const* d_in, const int* in_sizes, int n_in,
                              void* d_out, int out_size, void* d_ws, size_t ws_size,
                              hipStream_t stream) {
  const float* enc    = (const float*)d_in[0];
  const float* query  = (const float*)d_in[1];
  const float* cum    = (const float*)d_in[2];
  const int*   chars  = (const int*)d_in[3];
  // d_in[4] = t (unused)
  const float* conv_w = (const float*)d_in[5];
  const float* conv_b = (const float*)d_in[6];
  const float* L_w    = (const float*)d_in[7];
  const float* W_w    = (const float*)d_in[8];
  const float* W_b    = (const float*)d_in[9];
  const float* v_w    = (const float*)d_in[10];
  float* ws  = (float*)d_ws;
  float* out = (float*)d_out;

  hipLaunchKernelGGL(precompute_kernel, dim3(BB + 1), dim3(AD), 0, stream,
                     query, conv_w, conv_b, L_w, W_w, W_b, ws);
  hipLaunchKernelGGL(lsa_u_kernel, dim3(TT / 128, BB), dim3(256), 0, stream,
                     enc, cum, chars, v_w, ws, out);
  hipLaunchKernelGGL(smax_partial, dim3(8, BB), dim3(256), 0, stream, out, ws);
  hipLaunchKernelGGL(smax_norm, dim3(8, BB), dim3(256), 0, stream, out, ws);
}